// Round 1
// baseline (290.152 us; speedup 1.0000x reference)
//
#include <hip/hip_runtime.h>
#include <math.h>

// Problem constants: x [B=16, Cin=16, N=512, T=64], D=8, heads H=4, head_dim K=2
#define NPOS      524288   // B*T*N
#define NPAIR     8192     // B*N
#define CH_STRIDE 32768    // N*T  (channel stride in x)
#define B_STRIDE  524288   // Cin*N*T (batch stride in x)
#define BN_EPS    1e-5f
#define INV_NPOS  (1.0f / 524288.0f)

__device__ __forceinline__ float wave_red64(float v) {
    v += __shfl_xor(v, 32);
    v += __shfl_xor(v, 16);
    v += __shfl_xor(v, 8);
    v += __shfl_xor(v, 4);
    v += __shfl_xor(v, 2);
    v += __shfl_xor(v, 1);
    return v;
}

__device__ __forceinline__ float rlane(float v, int lane) {
    return __int_as_float(__builtin_amdgcn_readlane(__float_as_int(v), lane));
}

// ---------------- Kernel A: per-channel sum/sumsq of y = x@W + b for q,k,v ----------------
__global__ __launch_bounds__(256) void stats_qkv_kernel(
    const float* __restrict__ x,
    const float* __restrict__ Wq, const float* __restrict__ bq,
    const float* __restrict__ Wk, const float* __restrict__ bk,
    const float* __restrict__ Wv, const float* __restrict__ bv,
    float* __restrict__ stats /* [48]: sum[24], sumsq[24] */)
{
    float acc_s[24], acc_q[24];
#pragma unroll
    for (int j = 0; j < 24; ++j) { acc_s[j] = 0.f; acc_q[j] = 0.f; }

    int tid = blockIdx.x * 256 + threadIdx.x;
    int stride = gridDim.x * 256;
    for (int p = tid; p < NPOS; p += stride) {
        int b = p >> 15;           // / (N*T)
        int r = p & 32767;         // n*64 + t
        const float* xb = x + b * B_STRIDE + r;
        float xv[16];
#pragma unroll
        for (int c = 0; c < 16; ++c) xv[c] = xb[c * CH_STRIDE];
#pragma unroll
        for (int j = 0; j < 8; ++j) {
            float yq = bq[j], yk = bk[j], yv = bv[j];
#pragma unroll
            for (int c = 0; c < 16; ++c) {
                yq = fmaf(xv[c], Wq[c * 8 + j], yq);
                yk = fmaf(xv[c], Wk[c * 8 + j], yk);
                yv = fmaf(xv[c], Wv[c * 8 + j], yv);
            }
            acc_s[j]      += yq;  acc_q[j]      += yq * yq;
            acc_s[8 + j]  += yk;  acc_q[8 + j]  += yk * yk;
            acc_s[16 + j] += yv;  acc_q[16 + j] += yv * yv;
        }
    }

    __shared__ float red[4][48];
    int w = threadIdx.x >> 6, lane = threadIdx.x & 63;
#pragma unroll
    for (int j = 0; j < 24; ++j) {
        float vs = wave_red64(acc_s[j]);
        float vq = wave_red64(acc_q[j]);
        if (lane == 0) { red[w][j] = vs; red[w][24 + j] = vq; }
    }
    __syncthreads();
    if (threadIdx.x < 48) {
        float v = red[0][threadIdx.x] + red[1][threadIdx.x] + red[2][threadIdx.x] + red[3][threadIdx.x];
        atomicAdd(&stats[threadIdx.x], v);
    }
}

// ---------------- Kernel B: fold BN into effective weights for q,k,v ----------------
__global__ void finalize_qkv_kernel(
    const float* __restrict__ stats,
    const float* __restrict__ Wq, const float* __restrict__ bq,
    const float* __restrict__ gq, const float* __restrict__ betaq,
    const float* __restrict__ Wk, const float* __restrict__ bk,
    const float* __restrict__ gk, const float* __restrict__ betak,
    const float* __restrict__ Wv, const float* __restrict__ bv,
    const float* __restrict__ gv, const float* __restrict__ betav,
    float* __restrict__ effW /*[16*24] c-major*/, float* __restrict__ effB /*[24]*/)
{
    int j = threadIdx.x;
    if (j >= 24) return;
    int grp = j >> 3, jj = j & 7;
    const float* W  = (grp == 0) ? Wq : (grp == 1) ? Wk : Wv;
    const float* bb = (grp == 0) ? bq : (grp == 1) ? bk : bv;
    const float* g  = (grp == 0) ? gq : (grp == 1) ? gk : gv;
    const float* be = (grp == 0) ? betaq : (grp == 1) ? betak : betav;

    float mean = stats[j] * INV_NPOS;
    float var  = stats[24 + j] * INV_NPOS - mean * mean;
    float s    = g[jj] * rsqrtf(var + BN_EPS);
    for (int c = 0; c < 16; ++c) effW[c * 24 + j] = W[c * 8 + jj] * s;
    effB[j] = bb[jj] * s + be[jj] - mean * s;
}

// ---------------- Kernel C: fused qkv + attention; writes attn out + its stats ----------------
__global__ __launch_bounds__(256) void attn_kernel(
    const float* __restrict__ x,
    const float* __restrict__ effW, const float* __restrict__ effB,
    float* __restrict__ attnbuf /* [8192][64][8] */,
    float* __restrict__ statsA  /* [44]: sum[8], cross[36] */)
{
    float sumA[8], cross[36];
#pragma unroll
    for (int i = 0; i < 8; ++i) sumA[i] = 0.f;
#pragma unroll
    for (int i = 0; i < 36; ++i) cross[i] = 0.f;

    int w = threadIdx.x >> 6, lane = threadIdx.x & 63;
    int wgid = blockIdx.x * 4 + w;       // grid 1024 blocks -> 4096 waves, 2 iters

    for (int it = 0; it < 2; ++it) {
        int pair = wgid + it * 4096;
        int b = pair >> 9, n = pair & 511;
        const float* xb = x + b * B_STRIDE + n * 64 + lane;

        float xv[16];
#pragma unroll
        for (int c = 0; c < 16; ++c) xv[c] = xb[c * CH_STRIDE];

        // q,k,v = relu(x @ effW + effB)
        float qkv[24];
#pragma unroll
        for (int j = 0; j < 24; ++j) {
            float y = effB[j];
#pragma unroll
            for (int c = 0; c < 16; ++c) y = fmaf(xv[c], effW[c * 24 + j], y);
            qkv[j] = fmaxf(y, 0.f);
        }

        float out[8];
        // per head: online softmax WITHOUT max subtraction (scores bounded; post-BN-relu
        // q,k are O(1), score = q.k/2 << 80 so exp cannot overflow in f32)
#pragma unroll
        for (int h = 0; h < 4; ++h) {
            float q0 = qkv[2 * h] * 0.5f;
            float q1 = qkv[2 * h + 1] * 0.5f;
            float k0 = qkv[8 + 2 * h], k1 = qkv[8 + 2 * h + 1];
            float v0 = qkv[16 + 2 * h], v1 = qkv[16 + 2 * h + 1];
            float se0 = 0.f, se1 = 0.f;
            float o00 = 0.f, o01 = 0.f, o10 = 0.f, o11 = 0.f;
#pragma unroll 4
            for (int j = 0; j < 64; j += 2) {
                float e0 = __expf(fmaf(q0, rlane(k0, j), q1 * rlane(k1, j)));
                se0 += e0;
                o00 = fmaf(e0, rlane(v0, j), o00);
                o10 = fmaf(e0, rlane(v1, j), o10);
                float e1 = __expf(fmaf(q0, rlane(k0, j + 1), q1 * rlane(k1, j + 1)));
                se1 += e1;
                o01 = fmaf(e1, rlane(v0, j + 1), o01);
                o11 = fmaf(e1, rlane(v1, j + 1), o11);
            }
            float inv = 1.0f / (se0 + se1);
            out[2 * h]     = (o00 + o01) * inv;
            out[2 * h + 1] = (o10 + o11) * inv;
        }

        // store attention output (channel-contiguous for the final FC kernel)
        float4* dst = (float4*)(attnbuf + (size_t)pair * 512 + lane * 8);
        dst[0] = make_float4(out[0], out[1], out[2], out[3]);
        dst[1] = make_float4(out[4], out[5], out[6], out[7]);

        // accumulate stats for output BN (covariance trick)
        int cnt = 0;
#pragma unroll
        for (int i = 0; i < 8; ++i) {
            sumA[i] += out[i];
#pragma unroll
            for (int j2 = i; j2 < 8; ++j2) { cross[cnt] = fmaf(out[i], out[j2], cross[cnt]); ++cnt; }
        }
    }

    __shared__ float red[4][44];
#pragma unroll
    for (int i = 0; i < 8; ++i) {
        float v = wave_red64(sumA[i]);
        if (lane == 0) red[w][i] = v;
    }
#pragma unroll
    for (int i = 0; i < 36; ++i) {
        float v = wave_red64(cross[i]);
        if (lane == 0) red[w][8 + i] = v;
    }
    __syncthreads();
    if (threadIdx.x < 44) {
        float v = red[0][threadIdx.x] + red[1][threadIdx.x] + red[2][threadIdx.x] + red[3][threadIdx.x];
        atomicAdd(&statsA[threadIdx.x], v);
    }
}

// ---------------- Kernel D: fold BN into effective Wo,bo via covariance ----------------
__global__ void finalize_out_kernel(
    const float* __restrict__ statsA,
    const float* __restrict__ Wo, const float* __restrict__ bo,
    const float* __restrict__ go, const float* __restrict__ betao,
    float* __restrict__ effWo /*[8*16] i-major*/, float* __restrict__ effbo /*[16]*/)
{
    int d = threadIdx.x;
    if (d >= 16) return;
    float mA[8];
#pragma unroll
    for (int i = 0; i < 8; ++i) mA[i] = statsA[i] * INV_NPOS;

    float mean = bo[d];
#pragma unroll
    for (int i = 0; i < 8; ++i) mean = fmaf(mA[i], Wo[i * 16 + d], mean);

    float var = 0.f;
    int cnt = 0;
#pragma unroll
    for (int i = 0; i < 8; ++i) {
#pragma unroll
        for (int j = i; j < 8; ++j) {
            float cov = statsA[8 + cnt] * INV_NPOS - mA[i] * mA[j];
            ++cnt;
            float wterm = Wo[i * 16 + d] * Wo[j * 16 + d];
            var += (i == j) ? wterm * cov : 2.f * wterm * cov;
        }
    }
    float s = go[d] * rsqrtf(var + BN_EPS);
    for (int i = 0; i < 8; ++i) effWo[i * 16 + d] = Wo[i * 16 + d] * s;
    effbo[d] = bo[d] * s + betao[d] - mean * s;
}

// ---------------- Kernel E: final FC + BN + relu, transposed write ----------------
__global__ __launch_bounds__(256) void out_kernel(
    const float* __restrict__ attnbuf,
    const float* __restrict__ effWo, const float* __restrict__ effbo,
    float* __restrict__ outp)
{
    int w = threadIdx.x >> 6, lane = threadIdx.x & 63;
    int pair = blockIdx.x * 4 + w;      // grid 2048 -> 8192 pairs
    int b = pair >> 9, n = pair & 511;

    const float4* src = (const float4*)(attnbuf + (size_t)pair * 512 + lane * 8);
    float4 a0 = src[0], a1 = src[1];
    float a[8] = { a0.x, a0.y, a0.z, a0.w, a1.x, a1.y, a1.z, a1.w };

    float* ob = outp + b * B_STRIDE + n * 64 + lane;
#pragma unroll
    for (int d = 0; d < 16; ++d) {
        float o = effbo[d];
#pragma unroll
        for (int i = 0; i < 8; ++i) o = fmaf(a[i], effWo[i * 16 + d], o);
        ob[d * CH_STRIDE] = fmaxf(o, 0.f);
    }
}

extern "C" void kernel_launch(void* const* d_in, const int* in_sizes, int n_in,
                              void* d_out, int out_size, void* d_ws, size_t ws_size,
                              hipStream_t stream)
{
    const float* x     = (const float*)d_in[0];
    // d_in[1] = time_ind (unused by reference)
    const float* Wq    = (const float*)d_in[2];
    const float* bq    = (const float*)d_in[3];
    const float* gq    = (const float*)d_in[4];
    const float* betaq = (const float*)d_in[5];
    const float* Wk    = (const float*)d_in[6];
    const float* bk    = (const float*)d_in[7];
    const float* gk    = (const float*)d_in[8];
    const float* betak = (const float*)d_in[9];
    const float* Wv    = (const float*)d_in[10];
    const float* bv    = (const float*)d_in[11];
    const float* gv    = (const float*)d_in[12];
    const float* betav = (const float*)d_in[13];
    const float* Wo    = (const float*)d_in[14];
    const float* bo    = (const float*)d_in[15];
    const float* go    = (const float*)d_in[16];
    const float* betao = (const float*)d_in[17];

    float* ws      = (float*)d_ws;
    float* stats   = ws;          // 48 floats
    float* statsA  = ws + 48;     // 44 floats
    float* effW    = ws + 96;     // 384
    float* effB    = ws + 480;    // 24
    float* effWo   = ws + 512;    // 128
    float* effbo   = ws + 640;    // 16
    float* attnbuf = ws + 1024;   // 8192*64*8 = 4M floats (16 MiB)

    // zero the accumulator region (ws is poisoned 0xAA before every launch)
    hipMemsetAsync(d_ws, 0, 4096, stream);

    stats_qkv_kernel<<<512, 256, 0, stream>>>(x, Wq, bq, Wk, bk, Wv, bv, stats);
    finalize_qkv_kernel<<<1, 64, 0, stream>>>(stats, Wq, bq, gq, betaq,
                                              Wk, bk, gk, betak, Wv, bv, gv, betav,
                                              effW, effB);
    attn_kernel<<<1024, 256, 0, stream>>>(x, effW, effB, attnbuf, statsA);
    finalize_out_kernel<<<1, 64, 0, stream>>>(statsA, Wo, bo, go, betao, effWo, effbo);
    out_kernel<<<2048, 256, 0, stream>>>(attnbuf, effWo, effbo, (float*)d_out);
}